// Round 12
// baseline (133.841 us; speedup 1.0000x reference)
//
#include <hip/hip_runtime.h>
#include <stdint.h>

typedef __attribute__((ext_vector_type(8))) short short8;
typedef __attribute__((ext_vector_type(4))) float f32x4;
typedef __attribute__((ext_vector_type(8))) float f32x8;
typedef __attribute__((ext_vector_type(16))) float f32x16;
typedef __bf16 bf16x8_t __attribute__((ext_vector_type(8)));

#define NN 784              // 28*28
#define NA 28               // output rows a
#define ABYTES 16384        // W bytes per a: 16 K-steps x 1KB frag
#define NIMG 128            // images per block (4 waves x 32)
#define OT 14336            // one out-tile: 128 img x 28 cols x 4B

__device__ __forceinline__ unsigned short f2bf(float f) {
  unsigned int u = __float_as_uint(f);
  return (unsigned short)((u + 0x7FFFu + ((u >> 16) & 1u)) >> 16);  // RNE, finite
}

__device__ __forceinline__ short8 cvt8(f32x4 lo, f32x4 hi) {
  f32x8 f = {lo.x, lo.y, lo.z, lo.w, hi.x, hi.y, hi.z, hi.w};
  bf16x8_t b = __builtin_convertvector(f, bf16x8_t);   // v_cvt_pk_bf16_f32 (RNE)
  return __builtin_bit_cast(short8, b);
}

// First k-slot (32-wide) of output row a's 256-wide window covering 28(a-3)..28(a+4).
__host__ __device__ constexpr int slot0c(int a) {
  int t = 28 * a - 84;
  if (t < 0) t = 0;
  t >>= 5;
  if (t > 17) t = 17;
  return t;
}
// 3-iteration-deep x prefetch schedule.
__host__ __device__ constexpr int tgt3(int I) { int a2 = I + 3 > 27 ? 27 : I + 3; return slot0c(a2) + 7; }
__host__ __device__ constexpr bool xiss(int I) { return I >= 1 && tgt3(I) > tgt3(I - 1); }
__host__ __device__ constexpr bool xcv(int A)  { return A >= 4 && xiss(A - 3); }

// Bpack[a][step 0..15] = 1KB A-fragment for mfma_f32_32x32x16_bf16 (same as R10/R11).
__global__ void build_w_kernel(const float* __restrict__ pos2d,
                               const float* __restrict__ weight,
                               const float* __restrict__ ep,
                               unsigned short* __restrict__ Bpack) {
  int idx = blockIdx.x * 256 + threadIdx.x;   // 0 .. 28*16*512-1
  int u    = idx & 511;
  int frag = idx >> 9;           // a*16 + s2
  int s2 = frag & 15;
  int a  = frag >> 4;
  int j    = u & 7;
  int lane = u >> 3;
  int outcol = lane & 31;
  int kh     = lane >> 5;
  int kk = kh * 8 + j;
  int kglob = slot0c(a) * 32 + s2 * 16 + kk;
  float val = 0.f;
  if (outcol < 28 && kglob < NN) {
    float px = pos2d[2 * kglob + 0];
    float py = pos2d[2 * kglob + 1];
    float dx = (float)outcol - px;
    float dy = (float)a - py;
    float d2 = __fadd_rn(__fmul_rn(dx, dx), __fmul_rn(dy, dy));  // match np (no fma)
    if (d2 < 9.0f) {
      float en = fminf(ep[kglob], 0.f);
      val = expf(en * d2) * weight[a * 28 + outcol];
    }
  }
  Bpack[idx] = f2bf(val);
}

// One fully-unrolled a-iteration; ALL ring/stage indices compile-time.
template <int A>
struct It {
  static __device__ __forceinline__ void run(
      const float* __restrict__ xrow, const unsigned short* __restrict__ Bpack,
      char* __restrict__ wlds, char* __restrict__ olds,
      float* __restrict__ oblk, int tid, int lane,
      short8 (&rlo)[12], short8 (&rhi)[12],
      f32x4 (&stg)[3][4], f32x4 (&sr)[2][4]) {
    constexpr int T0 = slot0c(A);
    const int il = lane & 31;
    const int kh = lane >> 5;

    // 1) issue W(A+2) -> sr[A&1]  (consumed by ds_write at iter A+1: full-iter latency cover)
    if constexpr (A + 2 < NA) {
      const char* src = (const char*)Bpack + (A + 2) * ABYTES + tid * 16;
      #pragma unroll
      for (int r = 0; r < 4; ++r)
        sr[A & 1][r] = *(const f32x4*)(src + r * 4096);
    }
    // 2) cvt x slot staged 3 iters ago (JIT: first used by THIS iter's MFMAs)
    if constexpr (xcv(A)) {
      constexpr int S = tgt3(A - 3);
      rlo[S % 12] = cvt8(stg[A % 3][0], stg[A % 3][1]);
      if constexpr (S < 24) rhi[S % 12] = cvt8(stg[A % 3][2], stg[A % 3][3]);
      else                  rhi[S % 12] = short8{};      // k>=784 pad (W pad 0 too)
    }
    // 3) issue x loads for slot tgt3(A) (consumed at iter A+3)
    if constexpr (xiss(A)) {
      constexpr int S = tgt3(A);
      const float* p = xrow + S * 32 + kh * 8;
      stg[A % 3][0] = *(const f32x4*)p;
      stg[A % 3][1] = *(const f32x4*)(p + 4);
      if constexpr (S < 24) {
        stg[A % 3][2] = *(const f32x4*)(p + 16);
        stg[A % 3][3] = *(const f32x4*)(p + 20);
      }
    }

    // 4) compute a=A from LDS ring buf A%3 (16 frag reads + 16 MFMA)
    const char* wbuf = wlds + (A % 3) * ABYTES + lane * 16;
    f32x16 acc = {};
    __builtin_amdgcn_s_setprio(1);
#define KSTEP(s) { constexpr int SL = (T0 + ((s) >> 1)) % 12;                   \
    short8 wf = *(const short8*)(wbuf + (s) * 1024);                            \
    acc = __builtin_amdgcn_mfma_f32_32x32x16_bf16(                              \
        wf, ((s) & 1) ? rhi[SL] : rlo[SL], acc, 0, 0, 0); }
    KSTEP(0)  KSTEP(1)  KSTEP(2)  KSTEP(3)
    KSTEP(4)  KSTEP(5)  KSTEP(6)  KSTEP(7)
    KSTEP(8)  KSTEP(9)  KSTEP(10) KSTEP(11)
    KSTEP(12) KSTEP(13) KSTEP(14) KSTEP(15)
#undef KSTEP
    __builtin_amdgcn_s_setprio(0);

    // 5) ds_write W(A+1) (loaded at iter A-1; compiler-counted vmcnt, newer loads stay in flight)
    if constexpr (A + 1 < NA) {
      char* dst = wlds + ((A + 1) % 3) * ABYTES + tid * 16;
      #pragma unroll
      for (int r = 0; r < 4; ++r)
        *(f32x4*)(dst + r * 4096) = sr[(A + 1) & 1][r];
    }

    // 6) flush tile P=A-1 (written before barrier(A-1)): exact linear f32x4 copy
    if constexpr (A >= 1) {
      constexpr int P = A - 1;
      const char* src = olds + (P & 1) * OT;
      #pragma unroll
      for (int r = 0; r < 4; ++r) {
        int e = r * 256 + tid;                 // 896 granules = 128 img x 7
        if (r < 3 || e < 896) {
          int img = e / 7, u = e - img * 7;
          f32x4 v = *(const f32x4*)(src + img * 112 + u * 16);
          *(f32x4*)(oblk + (size_t)img * NN + P * 28 + u * 4) = v;
        }
      }
    }

    // 7) acc -> otile[A&1]: img = wave*32+il, cols 8g+4kh (<28)
    {
      char* ob = olds + (A & 1) * OT + ((tid >> 6) * 32 + il) * 112 + kh * 16;
      #pragma unroll
      for (int g = 0; g < 4; ++g)
        if (g < 3 || kh == 0) {
          f32x4 v = {acc[4 * g + 0], acc[4 * g + 1], acc[4 * g + 2], acc[4 * g + 3]};
          *(f32x4*)(ob + g * 32) = v;          // ds_write_b128
        }
    }

    __builtin_amdgcn_s_barrier();              // wbuf(A+1) ready; otile(A) complete
    It<A + 1>::run(xrow, Bpack, wlds, olds, oblk, tid, lane, rlo, rhi, stg, sr);
  }
};
template <>
struct It<NA> {
  static __device__ __forceinline__ void run(const float*, const unsigned short*,
                                             char*, char*, float*, int, int,
                                             short8 (&)[12], short8 (&)[12],
                                             f32x4 (&)[3][4], f32x4 (&)[2][4]) {}
};

// Banded GEMM, deep-pipelined. Block = 4 waves x 32 img. W: L2->reg (2 iters
// ahead) -> LDS ring-3. x: 12-slot register ring, 3 iters ahead. Out: double
// per-a LDS tile, linear f32x4 flush. ONE barrier/iter; every wait is a
// compiler-counted vmcnt/lgkmcnt on register deps.
__global__ __launch_bounds__(256, 2)
void gemm_kernel(const float* __restrict__ x,
                 const unsigned short* __restrict__ Bpack,
                 float* __restrict__ out) {
  __shared__ __align__(16) char wlds[3 * ABYTES];   // 48 KB W ring
  __shared__ __align__(16) char olds[2 * OT];       // 28 KB out tiles

  const int tid  = threadIdx.x;
  const int wave = tid >> 6;
  const int lane = tid & 63;
  const int il   = lane & 31;
  const int kh   = lane >> 5;

  const float* xrow = x + (size_t)(blockIdx.x * NIMG + wave * 32 + il) * NN;
  float*       oblk = out + (size_t)(blockIdx.x * NIMG) * NN;

  short8 rlo[12], rhi[12];
  f32x4  stg[3][4], sr[2][4];

  // W(0) -> regs (oldest loads)
  const char* bsrc = (const char*)Bpack + tid * 16;
  f32x4 w0r[4];
  #pragma unroll
  for (int r = 0; r < 4; ++r)
    w0r[r] = *(const f32x4*)(bsrc + r * 4096);

  // x prologue: slots 0..7, 2-slot-deep load/cvt pipeline through stg
#define PLOAD(S) { const float* p = xrow + (S) * 32 + kh * 8;                   \
    stg[(S) % 3][0] = *(const f32x4*)p;       stg[(S) % 3][1] = *(const f32x4*)(p + 4);  \
    stg[(S) % 3][2] = *(const f32x4*)(p + 16); stg[(S) % 3][3] = *(const f32x4*)(p + 20); }
#define PCVT(S)  { rlo[S] = cvt8(stg[(S) % 3][0], stg[(S) % 3][1]);             \
                   rhi[S] = cvt8(stg[(S) % 3][2], stg[(S) % 3][3]); }
  PLOAD(0) PLOAD(1) PCVT(0) PLOAD(2) PCVT(1) PLOAD(3) PCVT(2)
  PLOAD(4) PCVT(3)  PLOAD(5) PCVT(4) PLOAD(6) PCVT(5) PLOAD(7) PCVT(6) PCVT(7)
#undef PLOAD
#undef PCVT

  // W(1) -> sr[1] (ds_written at iter 0)
  #pragma unroll
  for (int r = 0; r < 4; ++r)
    sr[1][r] = *(const f32x4*)(bsrc + ABYTES + r * 4096);

  // W(0) -> ring buf 0
  #pragma unroll
  for (int r = 0; r < 4; ++r)
    *(f32x4*)(wlds + tid * 16 + r * 4096) = w0r[r];

  __syncthreads();

  It<0>::run(xrow, Bpack, wlds, olds, oblk, tid, lane, rlo, rhi, stg, sr);

  // epilogue: flush tile P = 27 (barrier at end of iter 27 already passed)
  {
    const char* src = olds + (27 & 1) * OT;
    #pragma unroll
    for (int r = 0; r < 4; ++r) {
      int e = r * 256 + tid;
      if (r < 3 || e < 896) {
        int img = e / 7, u = e - img * 7;
        f32x4 v = *(const f32x4*)(src + img * 112 + u * 16);
        *(f32x4*)(oblk + (size_t)img * NN + 27 * 28 + u * 4) = v;
      }
    }
  }
}

extern "C" void kernel_launch(void* const* d_in, const int* in_sizes, int n_in,
                              void* d_out, int out_size, void* d_ws, size_t ws_size,
                              hipStream_t stream) {
  const float* x      = (const float*)d_in[0];
  const float* pos2d  = (const float*)d_in[1];
  const float* weight = (const float*)d_in[2];
  const float* ep     = (const float*)d_in[3];
  float* out          = (float*)d_out;
  unsigned short* Bpack = (unsigned short*)d_ws;        // 28*16*512*2 = 458,752 B

  int batch = in_sizes[0] / NN;                         // 65536

  build_w_kernel<<<dim3((NA * 16 * 512) / 256), dim3(256), 0, stream>>>(
      pos2d, weight, ep, Bpack);
  gemm_kernel<<<dim3(batch / NIMG), dim3(256), 0, stream>>>(x, Bpack, out);
}

// Round 14
// 121.346 us; speedup vs baseline: 1.1030x; 1.1030x over previous
//
#include <hip/hip_runtime.h>
#include <stdint.h>

typedef __attribute__((ext_vector_type(8))) short short8;
typedef __attribute__((ext_vector_type(4))) float f32x4;
typedef __attribute__((ext_vector_type(8))) float f32x8;
typedef __attribute__((ext_vector_type(2))) float f32x2;
typedef __bf16 bf16x8_t __attribute__((ext_vector_type(8)));

#define NN 784              // 28*28
#define NA 28               // output rows a
#define NSLOT 8             // K-slots of 32 per a
#define FRAG_U16 512        // ushorts per 16x32 fragment
#define ABYTES (NSLOT * 2 * FRAG_U16 * 2)   // 16384 B of W per a
#define NIMG 128            // images per block (8 waves x 16)
#define OROW 232            // padded olds row bytes (56 cols used = 224; 8B-aligned rows)

__device__ __forceinline__ unsigned short f2bf(float f) {
  unsigned int u = __float_as_uint(f);
  return (unsigned short)((u + 0x7FFFu + ((u >> 16) & 1u)) >> 16);  // RNE, finite
}

__device__ __forceinline__ short8 cvt8(f32x4 lo, f32x4 hi) {
  f32x8 f = {lo.x, lo.y, lo.z, lo.w, hi.x, hi.y, hi.z, hi.w};
  bf16x8_t b = __builtin_convertvector(f, bf16x8_t);   // v_cvt_pk_bf16_f32 (RNE)
  return __builtin_bit_cast(short8, b);
}

// First stored k-slot for output row a (32-aligned window, slots 0..7 in [0,24]).
__host__ __device__ constexpr int slot0c(int a) {
  int t = 28 * a - 84;
  if (t < 0) t = 0;
  t >>= 5;
  if (t > 17) t = 17;
  return t;
}
// 2-iteration-ahead x prefetch schedule (R11-proven).
__host__ __device__ constexpr int tgtc(int I) { int a2 = I + 2 > 27 ? 27 : I + 2; return slot0c(a2) + 7; }
__host__ __device__ constexpr bool xissue(int I) { return I >= 1 && tgtc(I) > tgtc(I - 1); }
__host__ __device__ constexpr bool xcvt(int A)   { return A >= 3 && xissue(A - 2); }

// Bpack[a][s][nf] = 1KB MFMA W-fragment (16 outcols x 32 k) for 16x16x32.
// In-frag u16 idx for (outcol rl, k kk): ((kk>>3)*16 + rl)*8 + (kk&7).
// Value = weight[a*28+ncol] * W[a*28+ncol][kglob], 0 outside grid/band.
// (Verified layout from R5-R9.)
__global__ void build_w_kernel(const float* __restrict__ pos2d,
                               const float* __restrict__ weight,
                               const float* __restrict__ ep,
                               unsigned short* __restrict__ Bpack) {
  int idx = blockIdx.x * 256 + threadIdx.x;   // 0 .. 28*8*2*512-1
  int u    = idx & 511;
  int frag = idx >> 9;          // ((a*8 + s)*2 + nf)
  int nf = frag & 1;
  int s  = (frag >> 1) & 7;
  int a  = frag >> 4;
  int j8   = u & 7;
  int lane = u >> 3;
  int rl = lane & 15;
  int ch = lane >> 4;
  int kk = ch * 8 + j8;                        // 0..31
  int kglob = (slot0c(a) + s) * 32 + kk;
  int ncol  = nf * 16 + rl;
  float val = 0.f;
  if (ncol < 28 && kglob < NN) {
    float px = pos2d[2 * kglob + 0];
    float py = pos2d[2 * kglob + 1];
    float dx = (float)ncol - px;
    float dy = (float)a - py;
    float d2 = __fadd_rn(__fmul_rn(dx, dx), __fmul_rn(dy, dy));  // match np (no fma)
    if (d2 < 9.0f) {
      float en = fminf(ep[kglob], 0.f);
      val = expf(en * d2) * weight[a * 28 + ncol];
    }
  }
  Bpack[idx] = f2bf(val);
}

// One fully-unrolled a-iteration; all ring indices compile-time.
template <int A>
struct It {
  static __device__ __forceinline__ void run(
      const float* __restrict__ xrow, const unsigned short* __restrict__ Bpack,
      char* __restrict__ wlds, char* __restrict__ olds,
      float* __restrict__ oblk, int tid, int lane,
      short8 (&ring)[10], f32x4 (&stg)[2][2]) {
    constexpr int T0 = slot0c(A);
    const int rl = lane & 15;       // image slot / outcol-in-frag
    const int ch = lane >> 4;       // k-chunk of 8 / outcol quad

    // 1) issue W(A+1) -> regs (consumed by ds_write after the MFMA cluster)
    f32x4 s0, s1;
    if constexpr (A + 1 < NA) {
      const char* src = (const char*)Bpack + (A + 1) * ABYTES + tid * 16;
      s0 = *(const f32x4*)src;
      s1 = *(const f32x4*)(src + 8192);
    }
    // 2) cvt x slot staged 2 iters ago (JIT: first used by THIS iter)
    if constexpr (xcvt(A)) {
      constexpr int S = slot0c(A) + 7;
      if constexpr (S < 24) ring[S % 10] = cvt8(stg[A & 1][0], stg[A & 1][1]);
      else ring[S % 10] = (ch < 2) ? cvt8(stg[A & 1][0], stg[A & 1][1]) : short8{};
    }
    // 3) issue x loads for slot tgtc(A) (consumed at iter A+2)
    if constexpr (xissue(A)) {
      constexpr int S = tgtc(A);
      const float* p = xrow + S * 32 + ((S < 24) ? ch : (ch & 1)) * 8;
      stg[A & 1][0] = *(const f32x4*)p;
      stg[A & 1][1] = *(const f32x4*)(p + 4);
    }

    // 4) compute a=A from LDS ring buf A%3: 8 slots x 2 outcol-frags
    const char* wbuf = wlds + (A % 3) * ABYTES + lane * 16;
    f32x4 acc0 = {}, acc1 = {};
#define KSTEP(s) { constexpr int SL = (T0 + (s)) % 10;                          \
    short8 w0 = *(const short8*)(wbuf + ((s) * 2 + 0) * 1024);                  \
    short8 w1 = *(const short8*)(wbuf + ((s) * 2 + 1) * 1024);                  \
    acc0 = __builtin_amdgcn_mfma_f32_16x16x32_bf16(w0, ring[SL], acc0, 0, 0, 0);\
    acc1 = __builtin_amdgcn_mfma_f32_16x16x32_bf16(w1, ring[SL], acc1, 0, 0, 0); }
    KSTEP(0) KSTEP(1) KSTEP(2) KSTEP(3) KSTEP(4) KSTEP(5) KSTEP(6) KSTEP(7)
#undef KSTEP

    // 5) ds_write W(A+1) -> ring buf (A+1)%3
    if constexpr (A + 1 < NA) {
      char* dst = wlds + ((A + 1) % 3) * ABYTES + tid * 16;
      *(f32x4*)dst = s0;
      *(f32x4*)(dst + 8192) = s1;
    }

    // 6) acc -> otile: img = wave*16+rl, col-in-row = (A&1)*28 + outcol
    //    C frag: col = lane&15 = img, row(outcol) = ch*4 + reg.
    //    NOTE: OROW=232 is only 8B-aligned for odd img -> MUST use f32x2
    //    (ds_write_b64) stores, not f32x4 (b128 needs 16B align) -- R13's bug.
    {
      char* ob = olds + ((tid >> 6) * 16 + rl) * OROW + ((A & 1) * 28 + ch * 4) * 4;
      f32x2 a0lo = {acc0.x, acc0.y}, a0hi = {acc0.z, acc0.w};
      *(f32x2*)(ob + 0) = a0lo;                 // outcols ch*4+0..1
      *(f32x2*)(ob + 8) = a0hi;                 // outcols ch*4+2..3
      if (ch < 3) {
        f32x2 a1lo = {acc1.x, acc1.y}, a1hi = {acc1.z, acc1.w};
        *(f32x2*)(ob + 64) = a1lo;              // outcols 16+ch*4..+1 (<28)
        *(f32x2*)(ob + 72) = a1hi;
      }
    }

    __builtin_amdgcn_s_barrier();               // wbuf(A+1) ready; otile(A) done

    // 7) every odd A: flush pair P = A/2 (224B contiguous per image row)
    if constexpr (A & 1) {
      constexpr int P = A >> 1;
      #pragma unroll
      for (int r = 0; r < 7; ++r) {
        int e = r * 512 + tid;                  // 7*512 = 128*28 exactly
        int img = e / 28, u = e - img * 28;
        f32x2 v = *(const f32x2*)(olds + img * OROW + u * 8);
        *(f32x2*)((char*)(oblk + (size_t)img * NN + P * 56) + u * 8) = v;
      }
      __builtin_amdgcn_s_barrier();             // flush reads done before reuse
    }

    It<A + 1>::run(xrow, Bpack, wlds, olds, oblk, tid, lane, ring, stg);
  }
};
template <>
struct It<NA> {
  static __device__ __forceinline__ void run(const float*, const unsigned short*,
                                             char*, char*, float*, int, int,
                                             short8 (&)[10], f32x4 (&)[2][2]) {}
};

// Banded GEMM, occupancy-doubled (R11 structure, 16x16x32 MFMA).
// Block = 8 waves x 16 img = 128 images; 512 blocks; 2 blocks/CU x 8 waves
// = 16 waves/CU. W(a) 16KB reg-bounced into LDS ring-3 once per block per a;
// x in a 10-slot per-lane register ring (2 iters ahead, constexpr indices);
// out via LDS tile flushed every 2 a's as 224B-per-image runs.
__global__ __launch_bounds__(512, 4)
void gemm_kernel(const float* __restrict__ x,
                 const unsigned short* __restrict__ Bpack,
                 float* __restrict__ out) {
  __shared__ __align__(16) char wlds[3 * ABYTES];   // 48 KB W ring
  __shared__ __align__(16) char olds[NIMG * OROW];  // 29696 B out-tile

  const int tid  = threadIdx.x;
  const int wave = tid >> 6;
  const int lane = tid & 63;
  const int rl   = lane & 15;
  const int ch   = lane >> 4;

  const float* xrow = x + (size_t)(blockIdx.x * NIMG + wave * 16 + rl) * NN;
  float*       oblk = out + (size_t)(blockIdx.x * NIMG) * NN;

  short8 ring[10];
  f32x4  stg[2][2];

  // W(0) -> ring buf 0 (reg bounce)
  {
    const char* src = (const char*)Bpack + tid * 16;
    f32x4 a0 = *(const f32x4*)src;
    f32x4 a1 = *(const f32x4*)(src + 8192);
    *(f32x4*)(wlds + tid * 16) = a0;
    *(f32x4*)(wlds + tid * 16 + 8192) = a1;
  }

  // x prologue: slots 0..7 (k = 0..255, all valid)
#define PRO(S) { const float* p = xrow + (S) * 32 + ch * 8;                     \
    f32x4 lo = *(const f32x4*)p, hi = *(const f32x4*)(p + 4);                   \
    ring[S] = cvt8(lo, hi); }
  PRO(0) PRO(1) PRO(2) PRO(3) PRO(4) PRO(5) PRO(6) PRO(7)
#undef PRO

  __syncthreads();                          // ring buf 0 ready

  It<0>::run(xrow, Bpack, wlds, olds, oblk, tid, lane, ring, stg);
}

extern "C" void kernel_launch(void* const* d_in, const int* in_sizes, int n_in,
                              void* d_out, int out_size, void* d_ws, size_t ws_size,
                              hipStream_t stream) {
  const float* x      = (const float*)d_in[0];
  const float* pos2d  = (const float*)d_in[1];
  const float* weight = (const float*)d_in[2];
  const float* ep     = (const float*)d_in[3];
  float* out          = (float*)d_out;
  unsigned short* Bpack = (unsigned short*)d_ws;        // 28*8*2*512*2 = 458,752 B

  int batch = in_sizes[0] / NN;                         // 65536

  build_w_kernel<<<dim3((NA * NSLOT * 2 * FRAG_U16) / 256), dim3(256), 0, stream>>>(
      pos2d, weight, ep, Bpack);
  gemm_kernel<<<dim3(batch / NIMG), dim3(512), 0, stream>>>(x, Bpack, out);
}